// Round 1
// baseline (57.278 us; speedup 1.0000x reference)
//
#include <hip/hip_runtime.h>

// Gather rows from kv_buffer[POOL][576] at indices loc[N], split into
// out_nope[N][512] and out_rope[N][64] (concatenated flat in d_out).
// Pure memory-bound gather: one wave per row, float4 per lane.

#define POOL  131072
#define NROWS 65536
#define NOPE  512
#define ROPE  64
#define ROW_F4 ((NOPE + ROPE) / 4)   // 144 float4 per source row
#define NOPE_F4 (NOPE / 4)           // 128
#define ROPE_F4 (ROPE / 4)           // 16

__global__ __launch_bounds__(256) void gather_split_kernel(
    const float4* __restrict__ kv,      // [POOL * 144] float4
    const int*    __restrict__ loc,     // [NROWS]
    float4*       __restrict__ out_nope,// [NROWS * 128]
    float4*       __restrict__ out_rope)// [NROWS * 16]
{
    const int lane   = threadIdx.x & 63;
    const int wave   = (blockIdx.x * blockDim.x + threadIdx.x) >> 6;
    const int nwaves = (gridDim.x * blockDim.x) >> 6;

    for (int row = wave; row < NROWS; row += nwaves) {
        const int src = loc[row];  // broadcast load (all lanes same addr)
        const float4* __restrict__ sp = kv + (size_t)src * ROW_F4;
        float4* __restrict__ dn = out_nope + (size_t)row * NOPE_F4;
        float4* __restrict__ dr = out_rope + (size_t)row * ROPE_F4;

        // 144 chunks: lanes cover [0,64), [64,128), [128,144)
        #pragma unroll
        for (int base = 0; base < ROW_F4; base += 64) {
            const int c = base + lane;
            if (c < ROW_F4) {
                const float4 v = sp[c];
                if (c < NOPE_F4) dn[c] = v;
                else             dr[c - NOPE_F4] = v;
            }
        }
    }
}

extern "C" void kernel_launch(void* const* d_in, const int* in_sizes, int n_in,
                              void* d_out, int out_size, void* d_ws, size_t ws_size,
                              hipStream_t stream) {
    const float4* kv  = (const float4*)d_in[0];
    const int*    loc = (const int*)d_in[1];
    // d_in[2], d_in[3] are the zero-init cache tensors from the reference
    // signature — outputs actually go to d_out (concatenated: nope then rope).

    float4* out_nope = (float4*)d_out;
    float4* out_rope = (float4*)d_out + (size_t)NROWS * NOPE_F4;

    const int block = 256;
    const int grid  = 2048;  // 8192 waves, 8 rows each
    gather_split_kernel<<<grid, block, 0, stream>>>(kv, loc, out_nope, out_rope);
}

// Round 3
// 51.961 us; speedup vs baseline: 1.1023x; 1.1023x over previous
//
#include <hip/hip_runtime.h>

// Gather rows from kv_buffer[POOL][576] at indices loc[N], split into
// out_nope[N][512] and out_rope[N][64] (concatenated flat in d_out).
//
// Flat-chunk mapping: global thread t owns float4-chunk (t % 144) of row
// (t / 144). 100% lane utilization, uniform 18-iteration trip count,
// unrolled for memory-level parallelism. Non-temporal stores keep the
// 151 MB output stream from evicting pool rows out of L3 (touched pool
// working set ~119 MB < 256 MB L3, so repeated rows re-hit L3).

typedef float f32x4 __attribute__((ext_vector_type(4)));

#define POOL    131072
#define NROWS   65536
#define ROW_F4  144              // 576 floats / 4
#define NOPE_F4 128
#define ROPE_F4 16

#define BLOCKS  2048
#define TPB     256
#define NTHREADS (BLOCKS * TPB)                        // 524288
#define TOTAL_F4 ((size_t)NROWS * ROW_F4)              // 9437184
#define ITERS   (TOTAL_F4 / NTHREADS)                  // 18 exactly

__global__ __launch_bounds__(TPB) void gather_split_flat(
    const f32x4* __restrict__ kv,       // [POOL * 144]
    const int*   __restrict__ loc,      // [NROWS]
    f32x4*       __restrict__ out_nope, // [NROWS * 128]
    f32x4*       __restrict__ out_rope) // [NROWS * 16]
{
    const unsigned tid = blockIdx.x * TPB + threadIdx.x;

    #pragma unroll 6
    for (int k = 0; k < (int)ITERS; ++k) {
        const size_t t   = (size_t)tid + (size_t)k * NTHREADS;
        const unsigned row = (unsigned)(t / ROW_F4);
        const unsigned c   = (unsigned)(t - (size_t)row * ROW_F4);

        const int src = loc[row];
        const f32x4 v = kv[(size_t)src * ROW_F4 + c];

        if (c < NOPE_F4) {
            __builtin_nontemporal_store(v, &out_nope[(size_t)row * NOPE_F4 + c]);
        } else {
            __builtin_nontemporal_store(v, &out_rope[(size_t)row * ROPE_F4 + (c - NOPE_F4)]);
        }
    }
}

extern "C" void kernel_launch(void* const* d_in, const int* in_sizes, int n_in,
                              void* d_out, int out_size, void* d_ws, size_t ws_size,
                              hipStream_t stream) {
    const f32x4* kv  = (const f32x4*)d_in[0];
    const int*   loc = (const int*)d_in[1];

    f32x4* out_nope = (f32x4*)d_out;
    f32x4* out_rope = (f32x4*)d_out + (size_t)NROWS * NOPE_F4;

    gather_split_flat<<<BLOCKS, TPB, 0, stream>>>(kv, loc, out_nope, out_rope);
}

// Round 4
// 49.845 us; speedup vs baseline: 1.1491x; 1.0425x over previous
//
#include <hip/hip_runtime.h>

// Gather rows from kv_buffer[POOL][576] at indices loc[N], split into
// out_nope[N][512] and out_rope[N][64] (concatenated flat in d_out).
//
// Flat-chunk mapping: global thread t owns float4-chunk (t % 144) of row
// (t / 144). Fully unrolled 18-iteration schedule in two phases:
//   phase 1: all 18 loc[] loads (independent, L2-resident after warmup)
//   phase 2: all 18 kv gathers + nontemporal stores
// This maximizes outstanding VMEM (latency hiding) and removes the
// loc->kv dependent chain from the steady state. NT stores keep the
// 151 MB output stream from evicting pool rows out of L3.

typedef float f32x4 __attribute__((ext_vector_type(4)));

#define POOL    131072
#define NROWS   65536
#define ROW_F4  144              // 576 floats / 4
#define NOPE_F4 128
#define ROPE_F4 16

#define BLOCKS  2048
#define TPB     256
#define NTHREADS (BLOCKS * TPB)                        // 524288
#define TOTAL_F4 ((size_t)NROWS * ROW_F4)              // 9437184
#define ITERS   18                                     // TOTAL_F4 / NTHREADS exactly

__global__ __launch_bounds__(TPB) void gather_split_flat(
    const f32x4* __restrict__ kv,       // [POOL * 144]
    const int*   __restrict__ loc,      // [NROWS]
    f32x4*       __restrict__ out_nope, // [NROWS * 128]
    f32x4*       __restrict__ out_rope) // [NROWS * 16]
{
    const unsigned tid = blockIdx.x * TPB + threadIdx.x;

    unsigned row[ITERS], c[ITERS];
    int      src[ITERS];

    // Phase 1: compute coordinates, issue all loc loads (independent).
    #pragma unroll
    for (int k = 0; k < ITERS; ++k) {
        const size_t t = (size_t)tid + (size_t)k * NTHREADS;
        row[k] = (unsigned)(t / ROW_F4);
        c[k]   = (unsigned)(t - (size_t)row[k] * ROW_F4);
        src[k] = loc[row[k]];
    }

    // Phase 2: gather + nontemporal store.
    #pragma unroll
    for (int k = 0; k < ITERS; ++k) {
        const f32x4 v = kv[(size_t)src[k] * ROW_F4 + c[k]];
        if (c[k] < NOPE_F4) {
            __builtin_nontemporal_store(v, &out_nope[(size_t)row[k] * NOPE_F4 + c[k]]);
        } else {
            __builtin_nontemporal_store(v, &out_rope[(size_t)row[k] * ROPE_F4 + (c[k] - NOPE_F4)]);
        }
    }
}

extern "C" void kernel_launch(void* const* d_in, const int* in_sizes, int n_in,
                              void* d_out, int out_size, void* d_ws, size_t ws_size,
                              hipStream_t stream) {
    const f32x4* kv  = (const f32x4*)d_in[0];
    const int*   loc = (const int*)d_in[1];

    f32x4* out_nope = (f32x4*)d_out;
    f32x4* out_rope = (f32x4*)d_out + (size_t)NROWS * NOPE_F4;

    gather_split_flat<<<BLOCKS, TPB, 0, stream>>>(kv, loc, out_nope, out_rope);
}

// Round 5
// 49.713 us; speedup vs baseline: 1.1522x; 1.0027x over previous
//
#include <hip/hip_runtime.h>

// Gather rows from kv_buffer[POOL][576] at indices loc[N], split into
// out_nope[N][512] and out_rope[N][64] (concatenated flat in d_out).
//
// Flat-chunk mapping: global thread t owns float4-chunk (t % 144) of row
// (t / 144). Fully unrolled 18-iteration schedule in two phases:
//   phase 1: all 18 loc[] loads (independent, L2-resident)
//   phase 2: all 18 kv gathers + ONE branchless nontemporal store each
// Destination address is a pointer-select (cndmask), so boundary-straddling
// waves issue a single store instead of two exec-masked paths.
// NT stores keep the 151 MB output stream from evicting pool rows from L3
// (~21% of gathered rows are duplicates that can re-hit L3).

typedef float f32x4 __attribute__((ext_vector_type(4)));

#define POOL    131072
#define NROWS   65536
#define ROW_F4  144              // 576 floats / 4
#define NOPE_F4 128
#define ROPE_F4 16

#define BLOCKS  2048
#define TPB     256
#define NTHREADS (BLOCKS * TPB)                        // 524288
#define TOTAL_F4 ((size_t)NROWS * ROW_F4)              // 9437184
#define ITERS   18                                     // TOTAL_F4 / NTHREADS exactly

__global__ __launch_bounds__(TPB) void gather_split_flat(
    const f32x4* __restrict__ kv,       // [POOL * 144]
    const int*   __restrict__ loc,      // [NROWS]
    f32x4*       __restrict__ out_nope, // [NROWS * 128]
    f32x4*       __restrict__ out_rope) // [NROWS * 16]
{
    const unsigned tid = blockIdx.x * TPB + threadIdx.x;

    unsigned row[ITERS], c[ITERS];
    int      src[ITERS];

    // Phase 1: coordinates + all loc loads (independent).
    #pragma unroll
    for (int k = 0; k < ITERS; ++k) {
        const size_t t = (size_t)tid + (size_t)k * NTHREADS;
        row[k] = (unsigned)(t / ROW_F4);
        c[k]   = (unsigned)(t - (size_t)row[k] * ROW_F4);
        src[k] = loc[row[k]];
    }

    // Phase 2: gather + branchless single NT store.
    #pragma unroll
    for (int k = 0; k < ITERS; ++k) {
        const f32x4 v = kv[(size_t)src[k] * ROW_F4 + c[k]];
        f32x4* dn = &out_nope[(size_t)row[k] * NOPE_F4 + c[k]];
        f32x4* dr = &out_rope[(size_t)row[k] * ROPE_F4 + (c[k] - NOPE_F4)];
        f32x4* dst = (c[k] < NOPE_F4) ? dn : dr;   // cndmask on address
        __builtin_nontemporal_store(v, dst);
    }
}

extern "C" void kernel_launch(void* const* d_in, const int* in_sizes, int n_in,
                              void* d_out, int out_size, void* d_ws, size_t ws_size,
                              hipStream_t stream) {
    const f32x4* kv  = (const f32x4*)d_in[0];
    const int*   loc = (const int*)d_in[1];

    f32x4* out_nope = (f32x4*)d_out;
    f32x4* out_rope = (f32x4*)d_out + (size_t)NROWS * NOPE_F4;

    gather_split_flat<<<BLOCKS, TPB, 0, stream>>>(kv, loc, out_nope, out_rope);
}